// Round 1
// baseline (100.865 us; speedup 1.0000x reference)
//
#include <hip/hip_runtime.h>

#define SN 8      // samples per block
#define NCH 4     // hi-chunks over R's high 256 values
#define HPC 64    // hi values per chunk
#define BLK 256

__global__ __launch_bounds__(BLK) void fuzzy_main(
    const float* __restrict__ x, const float* __restrict__ center,
    const float* __restrict__ sigma, const float* __restrict__ W,
    const float* __restrict__ b, float* __restrict__ S /* [N][9] partial sums */)
{
    __shared__ float xs[SN][8];
    __shared__ float mg[SN][32];     // mg[s][m*4+j]
    __shared__ float ph[SN][HPC];    // p_hi for this chunk
    __shared__ float red[4][SN][9];  // cross-wave reduction

    const int t = threadIdx.x;
    const int bid = blockIdx.x;
    const int ch = bid & (NCH - 1);
    const int g = bid >> 2;
    const int n0 = g * SN;

    if (t < SN * 8) {
        int s = t >> 3, m = t & 7;
        xs[s][m] = x[(n0 + s) * 8 + m];
    }
    __syncthreads();
    if (t < SN * 32) {               // 256 threads: one mg value each
        int s = t >> 5, idx = t & 31;
        int m = idx >> 2;
        float d = xs[s][m] - center[idx];
        float sg = sigma[idx];
        mg[s][idx] = expf(-d * d * 0.5f * sg * sg);
    }
    __syncthreads();
    const int hi0 = ch * HPC;
    for (int k = t; k < SN * HPC; k += BLK) {   // 512 values, 2 per thread
        int s = k >> 6, h = k & (HPC - 1);
        int hi = hi0 + h;
        ph[s][h] = mg[s][(hi >> 6) & 3] * mg[s][4 + ((hi >> 4) & 3)] *
                   mg[s][8 + ((hi >> 2) & 3)] * mg[s][12 + (hi & 3)];
    }
    __syncthreads();

    // p_lo for lo = t (this thread's fixed low digits), per sample
    float pl[SN];
    {
        int i4 = (t >> 6) & 3, i5 = (t >> 4) & 3, i6 = (t >> 2) & 3, i7 = t & 3;
        #pragma unroll
        for (int s = 0; s < SN; ++s)
            pl[s] = mg[s][16 + i4] * mg[s][20 + i5] * mg[s][24 + i6] * mg[s][28 + i7];
    }

    float acc[SN][9];
    #pragma unroll
    for (int s = 0; s < SN; ++s)
        #pragma unroll
        for (int c = 0; c < 9; ++c) acc[s][c] = 0.f;

    // main loop: 64 hi values; coalesced W-row + b loads; 72 FMA per iter
    for (int h = 0; h < HPC; ++h) {
        const size_t row = (size_t)(hi0 + h) * 256 + t;
        const float4 w0 = *reinterpret_cast<const float4*>(W + row * 8);
        const float4 w1 = *reinterpret_cast<const float4*>(W + row * 8 + 4);
        const float bb = b[row];
        #pragma unroll
        for (int s = 0; s < SN; ++s) {
            const float p = ph[s][h];   // LDS broadcast (conflict-free)
            acc[s][0] += p * w0.x; acc[s][1] += p * w0.y;
            acc[s][2] += p * w0.z; acc[s][3] += p * w0.w;
            acc[s][4] += p * w1.x; acc[s][5] += p * w1.y;
            acc[s][6] += p * w1.z; acc[s][7] += p * w1.w;
            acc[s][8] += p * bb;
        }
    }

    // scale by p_lo and reduce across the block
    const int wv = t >> 6, lane = t & 63;
    #pragma unroll
    for (int s = 0; s < SN; ++s) {
        #pragma unroll
        for (int c = 0; c < 9; ++c) {
            float v = acc[s][c] * pl[s];
            #pragma unroll
            for (int o = 32; o > 0; o >>= 1) v += __shfl_xor(v, o, 64);
            if (lane == 0) red[wv][s][c] = v;
        }
    }
    __syncthreads();
    if (t < SN * 9) {
        int s = t / 9, c = t % 9;
        float v = red[0][s][c] + red[1][s][c] + red[2][s][c] + red[3][s][c];
        atomicAdd(&S[(size_t)(n0 + s) * 9 + c], v);
    }
}

__global__ void fuzzy_final(const float* __restrict__ x, const float* __restrict__ center,
                            const float* __restrict__ sigma, const float* __restrict__ S,
                            float* __restrict__ out, int N)
{
    int n = blockIdx.x * blockDim.x + threadIdx.x;
    if (n >= N) return;
    float xv[8];
    #pragma unroll
    for (int m = 0; m < 8; ++m) xv[m] = x[n * 8 + m];
    float denom = 1.f;
    #pragma unroll
    for (int m = 0; m < 8; ++m) {
        float ssum = 0.f;
        #pragma unroll
        for (int j = 0; j < 4; ++j) {
            float d = xv[m] - center[m * 4 + j];
            float sg = sigma[m * 4 + j];
            ssum += expf(-d * d * 0.5f * sg * sg);
        }
        denom *= ssum;   // sum_r fg[r] factorizes exactly
    }
    float num = S[(size_t)n * 9 + 8];
    #pragma unroll
    for (int m = 0; m < 8; ++m) num += xv[m] * S[(size_t)n * 9 + m];
    out[n] = num / denom;
}

extern "C" void kernel_launch(void* const* d_in, const int* in_sizes, int n_in,
                              void* d_out, int out_size, void* d_ws, size_t ws_size,
                              hipStream_t stream)
{
    const float* x      = (const float*)d_in[0];
    const float* center = (const float*)d_in[1];
    const float* sigma  = (const float*)d_in[2];
    const float* W      = (const float*)d_in[3];
    const float* b      = (const float*)d_in[4];
    float* out = (float*)d_out;
    float* S   = (float*)d_ws;          // N*9 floats of scratch
    const int N = in_sizes[0] / 8;      // 1024

    hipMemsetAsync(S, 0, (size_t)N * 9 * sizeof(float), stream);
    fuzzy_main<<<(N / SN) * NCH, BLK, 0, stream>>>(x, center, sigma, W, b, S);
    fuzzy_final<<<(N + BLK - 1) / BLK, BLK, 0, stream>>>(x, center, sigma, S, out, N);
}

// Round 2
// 87.509 us; speedup vs baseline: 1.1526x; 1.1526x over previous
//
#include <hip/hip_runtime.h>

#define SN 8      // samples per block
#define NCH 8     // hi-chunks over R's high 256 values
#define HPC 32    // hi values per chunk (256/NCH)
#define BLK 256

__global__ __launch_bounds__(BLK) void fuzzy_main(
    const float* __restrict__ x, const float* __restrict__ center,
    const float* __restrict__ sigma, const float* __restrict__ W,
    const float* __restrict__ b, float* __restrict__ S /* [NCH][N][9] */, int N)
{
    __shared__ float xs[SN][8];
    __shared__ float mg[SN][32];     // mg[s][m*4+j]
    __shared__ float ph[HPC][SN];    // p_hi for this chunk, [h][s] for b128 broadcast
    __shared__ float red[4][SN][9];  // cross-wave reduction

    const int t = threadIdx.x;
    const int bid = blockIdx.x;
    const int ch = bid & (NCH - 1);
    const int g = bid >> 3;          // log2(NCH)
    const int n0 = g * SN;

    if (t < SN * 8) {
        int s = t >> 3, m = t & 7;
        xs[s][m] = x[(n0 + s) * 8 + m];
    }
    __syncthreads();
    if (t < SN * 32) {               // 256 threads: one mg value each
        int s = t >> 5, idx = t & 31;
        int m = idx >> 2;
        float d = xs[s][m] - center[idx];
        float sg = sigma[idx];
        mg[s][idx] = expf(-d * d * 0.5f * sg * sg);
    }
    __syncthreads();
    const int hi0 = ch * HPC;
    for (int k = t; k < SN * HPC; k += BLK) {   // 256 values, 1 per thread
        int h = k >> 3, s = k & (SN - 1);
        int hi = hi0 + h;
        ph[h][s] = mg[s][(hi >> 6) & 3] * mg[s][4 + ((hi >> 4) & 3)] *
                   mg[s][8 + ((hi >> 2) & 3)] * mg[s][12 + (hi & 3)];
    }
    __syncthreads();

    // p_lo for lo = t (this thread's fixed low digits), per sample
    float pl[SN];
    {
        int i4 = (t >> 6) & 3, i5 = (t >> 4) & 3, i6 = (t >> 2) & 3, i7 = t & 3;
        #pragma unroll
        for (int s = 0; s < SN; ++s)
            pl[s] = mg[s][16 + i4] * mg[s][20 + i5] * mg[s][24 + i6] * mg[s][28 + i7];
    }

    float acc[SN][9];
    #pragma unroll
    for (int s = 0; s < SN; ++s)
        #pragma unroll
        for (int c = 0; c < 9; ++c) acc[s][c] = 0.f;

    // main loop: HPC hi values; coalesced W-row + b loads; 72 FMA per iter
    #pragma unroll 2
    for (int h = 0; h < HPC; ++h) {
        const size_t row = (size_t)(hi0 + h) * 256 + t;
        const float4 w0 = *reinterpret_cast<const float4*>(W + row * 8);
        const float4 w1 = *reinterpret_cast<const float4*>(W + row * 8 + 4);
        const float bb = b[row];
        const float4 pA = *reinterpret_cast<const float4*>(&ph[h][0]);  // broadcast
        const float4 pB = *reinterpret_cast<const float4*>(&ph[h][4]);
        const float pv[SN] = {pA.x, pA.y, pA.z, pA.w, pB.x, pB.y, pB.z, pB.w};
        #pragma unroll
        for (int s = 0; s < SN; ++s) {
            const float p = pv[s];
            acc[s][0] += p * w0.x; acc[s][1] += p * w0.y;
            acc[s][2] += p * w0.z; acc[s][3] += p * w0.w;
            acc[s][4] += p * w1.x; acc[s][5] += p * w1.y;
            acc[s][6] += p * w1.z; acc[s][7] += p * w1.w;
            acc[s][8] += p * bb;
        }
    }

    // Reduction. Phase A: fold p_lo, butterfly over lane bits 3,4,5.
    // After this, lane l holds sum over lanes sharing (l&7), for every (s,c).
    const int wv = t >> 6, lane = t & 63;
    float v[SN][9];
    #pragma unroll
    for (int s = 0; s < SN; ++s)
        #pragma unroll
        for (int c = 0; c < 9; ++c) {
            float u = acc[s][c] * pl[s];
            u += __shfl_xor(u, 8, 64);
            u += __shfl_xor(u, 16, 64);
            u += __shfl_xor(u, 32, 64);
            v[s][c] = u;
        }

    // Phase B: lane l=8j+k adopts sample row j, then butterfly over bits 0,1,2
    // (sums the 8 lane-classes k) -> every lane in group j holds the full
    // 64-lane sum for s=j, all 9 c.
    const int sstar = lane >> 3;
    float w[9];
    #pragma unroll
    for (int c = 0; c < 9; ++c) w[c] = v[0][c];
    #pragma unroll
    for (int s = 1; s < SN; ++s) {
        const bool m = (sstar == s);
        #pragma unroll
        for (int c = 0; c < 9; ++c) w[c] = m ? v[s][c] : w[c];
    }
    #pragma unroll
    for (int c = 0; c < 9; ++c) {
        w[c] += __shfl_xor(w[c], 1, 64);
        w[c] += __shfl_xor(w[c], 2, 64);
        w[c] += __shfl_xor(w[c], 4, 64);
    }
    {
        const int k = lane & 7;      // lane 8j+k writes c=k; lane 8j+7 also c=8
        red[wv][sstar][k] = w[k];    // k is runtime -> but w[] indexed by k... avoid scratch:
    }
    __syncthreads();
    // NOTE: w[k] with runtime k would go to scratch; do compile-time select instead.
    // (overwrite above with correct masked writes)
    {
        const int k = lane & 7;
        float wk = w[0];
        #pragma unroll
        for (int c = 1; c < 8; ++c) wk = (k == c) ? w[c] : wk;
        red[wv][sstar][k] = wk;
        if (k == 7) red[wv][sstar][8] = w[8];
    }
    __syncthreads();
    if (t < SN * 9) {
        int s = t / 9, c = t % 9;
        float sum = red[0][s][c] + red[1][s][c] + red[2][s][c] + red[3][s][c];
        S[((size_t)ch * N + n0 + s) * 9 + c] = sum;
    }
}

__global__ void fuzzy_final(const float* __restrict__ x, const float* __restrict__ center,
                            const float* __restrict__ sigma, const float* __restrict__ S,
                            float* __restrict__ out, int N)
{
    int n = blockIdx.x * blockDim.x + threadIdx.x;
    if (n >= N) return;
    float xv[8];
    #pragma unroll
    for (int m = 0; m < 8; ++m) xv[m] = x[n * 8 + m];
    float denom = 1.f;
    #pragma unroll
    for (int m = 0; m < 8; ++m) {
        float ssum = 0.f;
        #pragma unroll
        for (int j = 0; j < 4; ++j) {
            float d = xv[m] - center[m * 4 + j];
            float sg = sigma[m * 4 + j];
            ssum += expf(-d * d * 0.5f * sg * sg);
        }
        denom *= ssum;   // sum_r fg[r] factorizes exactly
    }
    float sc[9];
    #pragma unroll
    for (int c = 0; c < 9; ++c) sc[c] = 0.f;
    #pragma unroll
    for (int ch = 0; ch < NCH; ++ch) {
        const float* p = S + ((size_t)ch * N + n) * 9;
        #pragma unroll
        for (int c = 0; c < 9; ++c) sc[c] += p[c];
    }
    float num = sc[8];
    #pragma unroll
    for (int m = 0; m < 8; ++m) num += xv[m] * sc[m];
    out[n] = num / denom;
}

extern "C" void kernel_launch(void* const* d_in, const int* in_sizes, int n_in,
                              void* d_out, int out_size, void* d_ws, size_t ws_size,
                              hipStream_t stream)
{
    const float* x      = (const float*)d_in[0];
    const float* center = (const float*)d_in[1];
    const float* sigma  = (const float*)d_in[2];
    const float* W      = (const float*)d_in[3];
    const float* b      = (const float*)d_in[4];
    float* out = (float*)d_out;
    float* S   = (float*)d_ws;          // NCH*N*9 floats; every slot written -> no memset
    const int N = in_sizes[0] / 8;      // 1024

    fuzzy_main<<<(N / SN) * NCH, BLK, 0, stream>>>(x, center, sigma, W, b, S, N);
    fuzzy_final<<<(N + BLK - 1) / BLK, BLK, 0, stream>>>(x, center, sigma, S, out, N);
}